// Round 3
// baseline (543.986 us; speedup 1.0000x reference)
//
#include <hip/hip_runtime.h>
#include <hip/hip_bf16.h>

#define T_SEQ   2048
#define HIDDEN  2048
#define NUM_H   32
#define NUM_KV  8
#define HD      128
#define Q_SIZE  4096
#define QKV_N   6144

typedef __bf16 bf16;
typedef __bf16 bf16x8 __attribute__((ext_vector_type(8)));
typedef float  floatx4 __attribute__((ext_vector_type(4)));

#define GLOBAL_AS(p) ((const __attribute__((address_space(1))) void*)(p))
#define LDS_AS(p)    ((__attribute__((address_space(3))) void*)(p))

// ---------------------------------------------------------------------------
// Dtype detection: inspect exponent fields of the first 512 uint16 words of
// wqkv (values ~N(0, 0.02^2)). bf16 data: ~all words have exponent 113..124.
// fp32 data: odd words (fp32 high halves) look like bf16, even words are
// mantissa junk with uniform exponents -> only ~58% pass. flag=1 => bf16.
// ---------------------------------------------------------------------------
__global__ void detect_dtype(const unsigned short* __restrict__ wq, int* flagp)
{
    const int lane = threadIdx.x;   // 64 threads
    int cnt = 0;
    for (int i = lane; i < 512; i += 64) {
        int ef = (wq[i] >> 7) & 0xFF;
        if (ef >= 90 && ef <= 130) cnt++;
    }
    #pragma unroll
    for (int m = 32; m; m >>= 1) cnt += __shfl_xor(cnt, m);
    if (lane == 0) *flagp = (cnt >= 430) ? 1 : 0;
}

// ---------------------------------------------------------------------------
// Canonicalize all float inputs into bf16 workspace copies.
// flag=1: inputs already bf16 -> vector copy. flag=0: fp32 -> convert.
// Concatenated element ranges: hidden 4194304 | wqkv 12582912 | wo 8388608 |
// qnw 128 | knw 128  (total 25166080; 8 elems/thread).
// ---------------------------------------------------------------------------
__global__ __launch_bounds__(256) void convert_all(
    const void* __restrict__ h, const void* __restrict__ wq,
    const void* __restrict__ wo_, const void* __restrict__ qn,
    const void* __restrict__ kn,
    bf16* __restrict__ hb, bf16* __restrict__ wqb, bf16* __restrict__ wob,
    bf16* __restrict__ qnb, bf16* __restrict__ knb, const int* flagp)
{
    long e = ((long)blockIdx.x * 256 + threadIdx.x) * 8;
    const void* src; bf16* dst; long off;
    if      (e < 4194304)  { src = h;   dst = hb;  off = e; }
    else if (e < 16777216) { src = wq;  dst = wqb; off = e - 4194304; }
    else if (e < 25165824) { src = wo_; dst = wob; off = e - 16777216; }
    else if (e < 25165952) { src = qn;  dst = qnb; off = e - 25165824; }
    else if (e < 25166080) { src = kn;  dst = knb; off = e - 25165952; }
    else return;

    if (*flagp) {
        *(bf16x8*)(dst + off) = *(const bf16x8*)((const bf16*)src + off);
    } else {
        const float* f = (const float*)src + off;
        bf16x8 v;
        #pragma unroll
        for (int i = 0; i < 8; ++i) v[i] = (bf16)f[i];
        *(bf16x8*)(dst + off) = v;
    }
}

// ---------------------------------------------------------------------------
// NT GEMM: C[M,N] = A[M,K] * B[N,K]^T, bf16 in, fp32 acc.
// m97 structure: 128x128 tile, BK=32, 4 waves (2x2 of 64x64), 16x16x32 MFMA,
// global_load_lds width-16 staging. A row stride lda.
// is_final: epilogue stores fp32 to C when *flagp==0, else bf16.
// ---------------------------------------------------------------------------
__global__ __launch_bounds__(256) void gemm_bt(
    const bf16* __restrict__ A, const bf16* __restrict__ B,
    void* __restrict__ Cv, int M, int N, int K, int lda,
    const int* flagp, int is_final)
{
    __shared__ bf16 As[128 * 32];
    __shared__ bf16 Bs[128 * 32];

    const int tid  = threadIdx.x;
    const int wave = tid >> 6, lane = tid & 63;
    const int quad = lane >> 4, l16 = lane & 15;
    const int wm = (wave & 1) * 64, wn = (wave >> 1) * 64;
    const long baseM = (long)blockIdx.x * 128;
    const long baseN = (long)blockIdx.y * 128;
    const int  bf_out = is_final ? *flagp : 1;

    const int  srow = wave * 16 + (lane >> 2);   // 0..63
    const int  scol = (lane & 3) * 8;            // 0,8,16,24
    const long aoff0 = (baseM + srow) * (long)lda + scol;
    const long aoff1 = (baseM + 64 + srow) * (long)lda + scol;
    const long boff0 = (baseN + srow) * (long)K + scol;
    const long boff1 = (baseN + 64 + srow) * (long)K + scol;
    const int  lds0 = wave * 512;        // elems; hw adds lane*16B
    const int  lds1 = 2048 + wave * 512;

    floatx4 acc[4][4] = {};

    for (int k0 = 0; k0 < K; k0 += 32) {
        __builtin_amdgcn_global_load_lds(GLOBAL_AS(A + aoff0 + k0), LDS_AS(As + lds0), 16, 0, 0);
        __builtin_amdgcn_global_load_lds(GLOBAL_AS(A + aoff1 + k0), LDS_AS(As + lds1), 16, 0, 0);
        __builtin_amdgcn_global_load_lds(GLOBAL_AS(B + boff0 + k0), LDS_AS(Bs + lds0), 16, 0, 0);
        __builtin_amdgcn_global_load_lds(GLOBAL_AS(B + boff1 + k0), LDS_AS(Bs + lds1), 16, 0, 0);
        __syncthreads();

        bf16x8 af[4], bfr[4];
        #pragma unroll
        for (int i = 0; i < 4; ++i)
            af[i] = *(const bf16x8*)(As + (wm + i * 16 + l16) * 32 + quad * 8);
        #pragma unroll
        for (int j = 0; j < 4; ++j)
            bfr[j] = *(const bf16x8*)(Bs + (wn + j * 16 + l16) * 32 + quad * 8);

        #pragma unroll
        for (int i = 0; i < 4; ++i)
            #pragma unroll
            for (int j = 0; j < 4; ++j)
                acc[i][j] = __builtin_amdgcn_mfma_f32_16x16x32_bf16(af[i], bfr[j], acc[i][j], 0, 0, 0);
        __syncthreads();
    }

    // epilogue: C/D layout col=lane&15, row=quad*4+reg
    #pragma unroll
    for (int i = 0; i < 4; ++i)
        #pragma unroll
        for (int j = 0; j < 4; ++j)
            #pragma unroll
            for (int r = 0; r < 4; ++r) {
                long row = baseM + wm + i * 16 + quad * 4 + r;
                long col = baseN + wn + j * 16 + l16;
                if (bf_out) ((bf16*)Cv)[row * (long)N + col] = (bf16)acc[i][j][r];
                else       ((float*)Cv)[row * (long)N + col] = acc[i][j][r];
            }
}

// ---------------------------------------------------------------------------
// In-place RMSNorm + RoPE on the q (cols 0..4095) and k (cols 4096..5119)
// sections of qkv[t][6144]. One block per token, 4 waves; wave handles one
// 128-wide head-unit at a time; lane i holds elems (i, i+64).
// ---------------------------------------------------------------------------
__global__ __launch_bounds__(256) void qkv_post(
    bf16* __restrict__ qkv, const int* __restrict__ positions,
    const bf16* __restrict__ qnw, const bf16* __restrict__ knw)
{
    const int t = blockIdx.x;
    const int tid = threadIdx.x, wave = tid >> 6, lane = tid & 63;
    const float pos = (float)positions[t];

    const float inv = expf(-(float)lane * (float)(9.210340371976184 / 64.0));
    float sn, cs;
    sincosf(pos * inv, &sn, &cs);

    bf16* row = qkv + (long)t * QKV_N;

    for (int u = wave; u < 40; u += 4) {
        bf16* p       = (u < 32) ? row + u * HD : row + Q_SIZE + (u - 32) * HD;
        const bf16* w = (u < 32) ? qnw : knw;
        float x1 = (float)p[lane], x2 = (float)p[lane + 64];
        float ss = x1 * x1 + x2 * x2;
        #pragma unroll
        for (int m = 32; m; m >>= 1) ss += __shfl_xor(ss, m);
        float rr = rsqrtf(ss * (1.f / 128.f) + 1e-6f);
        float y1 = x1 * rr * (float)w[lane];
        float y2 = x2 * rr * (float)w[lane + 64];
        p[lane]      = (bf16)(y1 * cs - y2 * sn);
        p[lane + 64] = (bf16)(y2 * cs + y1 * sn);
    }
}

// ---------------------------------------------------------------------------
// Causal flash attention, GQA 32/8, D=128, directly on the token-major qkv
// buffer (row stride 6144). Q at col h*128, K at 4096+kvh*128, V at
// 5120+kvh*128. O written IN PLACE over the Q columns (each block reads only
// the Q cells it overwrites, read-before-write by program order).
// ---------------------------------------------------------------------------
__global__ __launch_bounds__(256) void attn(bf16* qkv)
{
    constexpr int KSTR = 136;   // 128 + 8 pad
    constexpr int PSTR = 72;    // 64 + 8 pad
    __shared__ bf16 Ks[64 * KSTR];
    __shared__ bf16 Vt[128 * 64];        // [d][time], xor-swizzled blocks of 8
    __shared__ bf16 Ps[4][16 * PSTR];

    const int tid  = threadIdx.x, wave = tid >> 6, lane = tid & 63;
    const int quad = lane >> 4, l16 = lane & 15;
    const int h = blockIdx.y, kvh = h >> 2;
    const int q0 = blockIdx.x * 64;
    const float scale = 0.08838834764831845f;  // 128^-0.5

    bf16x8 qf[4];
    {
        const bf16* qb = qkv + (long)(q0 + wave * 16 + l16) * QKV_N + h * HD + quad * 8;
        #pragma unroll
        for (int ks = 0; ks < 4; ++ks) qf[ks] = *(const bf16x8*)(qb + ks * 32);
    }

    floatx4 oacc[8] = {};
    float mrow[4] = {-1e30f, -1e30f, -1e30f, -1e30f};
    float lrow[4] = {0.f, 0.f, 0.f, 0.f};

    const int sr = tid >> 4;          // staging row base (+ it*16)
    const int sc = (tid & 15) * 8;    // staging col (d)

    for (int kt = 0; kt <= (int)blockIdx.x; ++kt) {
        const int k0 = kt * 64;
        const bf16* kg = qkv + (long)k0 * QKV_N + Q_SIZE + kvh * HD;
        const bf16* vg = kg + NUM_KV * HD;

        #pragma unroll
        for (int it = 0; it < 4; ++it) {
            int r = it * 16 + sr;
            bf16x8 k8 = *(const bf16x8*)(kg + (long)r * QKV_N + sc);
            *(bf16x8*)(Ks + r * KSTR + sc) = k8;
            bf16x8 v8 = *(const bf16x8*)(vg + (long)r * QKV_N + sc);
            #pragma unroll
            for (int jj = 0; jj < 8; ++jj) {
                int d = sc + jj;
                Vt[d * 64 + ((((r >> 3) ^ ((d >> 3) & 7)) << 3) | (r & 7))] = v8[jj];
            }
        }
        __syncthreads();

        // S = Q K^T
        floatx4 sacc[4] = {};
        #pragma unroll
        for (int ks = 0; ks < 4; ++ks)
            #pragma unroll
            for (int j = 0; j < 4; ++j) {
                bf16x8 b = *(const bf16x8*)(Ks + (j * 16 + l16) * KSTR + ks * 32 + quad * 8);
                sacc[j] = __builtin_amdgcn_mfma_f32_16x16x32_bf16(qf[ks], b, sacc[j], 0, 0, 0);
            }

        // online softmax
        float alpha[4];
        #pragma unroll
        for (int r = 0; r < 4; ++r) {
            const int qrow = q0 + wave * 16 + quad * 4 + r;
            float sv[4], mx = -1e30f;
            #pragma unroll
            for (int j = 0; j < 4; ++j) {
                float s = sacc[j][r] * scale;
                if (k0 + j * 16 + l16 > qrow) s = -1e30f;
                sv[j] = s;
                mx = fmaxf(mx, s);
            }
            #pragma unroll
            for (int mm = 1; mm < 16; mm <<= 1) mx = fmaxf(mx, __shfl_xor(mx, mm));
            float mnew = fmaxf(mrow[r], mx);
            alpha[r] = __expf(mrow[r] - mnew);
            float rs = 0.f;
            #pragma unroll
            for (int j = 0; j < 4; ++j) {
                float e = __expf(sv[j] - mnew);
                rs += e;
                Ps[wave][(quad * 4 + r) * PSTR + j * 16 + l16] = (bf16)e;
            }
            #pragma unroll
            for (int mm = 1; mm < 16; mm <<= 1) rs += __shfl_xor(rs, mm);
            lrow[r] = lrow[r] * alpha[r] + rs;
            mrow[r] = mnew;
        }

        #pragma unroll
        for (int vj = 0; vj < 8; ++vj)
            #pragma unroll
            for (int r = 0; r < 4; ++r) oacc[vj][r] *= alpha[r];

        // guarantee P-store visibility before the A-operand reads below
        __syncthreads();

        // O += P V
        #pragma unroll
        for (int ks2 = 0; ks2 < 2; ++ks2) {
            bf16x8 pa = *(const bf16x8*)(&Ps[wave][l16 * PSTR + ks2 * 32 + quad * 8]);
            const int kb = ks2 * 32 + quad * 8;
            #pragma unroll
            for (int vj = 0; vj < 8; ++vj) {
                int n = vj * 16 + l16;
                bf16x8 b = *(const bf16x8*)(Vt + n * 64 + ((((kb >> 3) ^ ((n >> 3) & 7)) << 3)));
                oacc[vj] = __builtin_amdgcn_mfma_f32_16x16x32_bf16(pa, b, oacc[vj], 0, 0, 0);
            }
        }
        __syncthreads();
    }

    #pragma unroll
    for (int vj = 0; vj < 8; ++vj)
        #pragma unroll
        for (int r = 0; r < 4; ++r) {
            long row = q0 + wave * 16 + quad * 4 + r;
            qkv[row * (long)QKV_N + h * HD + vj * 16 + l16] = (bf16)(oacc[vj][r] / lrow[r]);
        }
}

// ---------------------------------------------------------------------------
extern "C" void kernel_launch(void* const* d_in, const int* in_sizes, int n_in,
                              void* d_out, int out_size, void* d_ws, size_t ws_size,
                              hipStream_t stream)
{
    const int* positions = (const int*)d_in[0];

    char* ws = (char*)d_ws;
    bf16* qkv  = (bf16*)(ws);              // [2048][6144]  25165824 B
    bf16* hb   = (bf16*)(ws + 25165824);   // [2048][2048]   8388608 B
    bf16* wqb  = (bf16*)(ws + 33554432);   // [6144][2048]  25165824 B
    bf16* wob  = (bf16*)(ws + 58720256);   // [2048][4096]  16777216 B
    bf16* qnb  = (bf16*)(ws + 75497472);   // [128]
    bf16* knb  = (bf16*)(ws + 75497728);   // [128]
    int*  flag = (int*) (ws + 75497984);

    detect_dtype<<<dim3(1), dim3(64), 0, stream>>>((const unsigned short*)d_in[2], flag);
    convert_all<<<dim3(12289), dim3(256), 0, stream>>>(
        d_in[1], d_in[2], d_in[3], d_in[4], d_in[5],
        hb, wqb, wob, qnb, knb, flag);

    dim3 blk(256);
    gemm_bt<<<dim3(T_SEQ / 128, QKV_N / 128), blk, 0, stream>>>(
        hb, wqb, qkv, T_SEQ, QKV_N, HIDDEN, HIDDEN, flag, 0);
    qkv_post<<<dim3(T_SEQ), blk, 0, stream>>>(qkv, positions, qnb, knb);
    attn<<<dim3(T_SEQ / 64, NUM_H), blk, 0, stream>>>(qkv);
    gemm_bt<<<dim3(T_SEQ / 128, HIDDEN / 128), blk, 0, stream>>>(
        qkv, wob, d_out, T_SEQ, HIDDEN, Q_SIZE, QKV_N, flag, 1);
}